// Round 4
// baseline (24261.647 us; speedup 1.0000x reference)
//
#include <hip/hip_runtime.h>
#include <cmath>

namespace {

constexpr int Tn = 64;
constexpr int Bn = 512;
constexpr int Xn = 784;
constexpr int XnP = 800;
constexpr int Fn = 64;
constexpr int Zn = 64;
constexpr int Hn = 512;
constexpr unsigned NBLK = 192;   // persistent grid: < 256 CUs -> co-resident

typedef unsigned short us;
typedef __attribute__((ext_vector_type(8))) short bf16x8;
typedef __attribute__((ext_vector_type(4))) float f32x4;

__device__ __forceinline__ us f2b(float v) {
  unsigned int u = __float_as_uint(v);
  return (us)((u + 0x7FFFu + ((u >> 16) & 1u)) >> 16);
}
__device__ __forceinline__ float b2f(us u) { return __uint_as_float(((unsigned int)u) << 16); }
__device__ __forceinline__ float sigmf(float v) { return 1.0f / (1.0f + __expf(-v)); }
__device__ __forceinline__ float splusf(float v) {
  return v > 0.0f ? (v + log1pf(__expf(-v))) : log1pf(__expf(v));
}
__device__ __forceinline__ float block_sum(float v, float* red) {
  #pragma unroll
  for (int off = 32; off > 0; off >>= 1) v += __shfl_down(v, off, 64);
  if ((threadIdx.x & 63) == 0) red[threadIdx.x >> 6] = v;
  __syncthreads();
  float s = 0.0f;
  if (threadIdx.x == 0) s = red[0] + red[1] + red[2] + red[3];
  return s;
}

// device-scope sense-reversal grid barrier (all NBLK blocks co-resident)
__device__ __forceinline__ void gridbar(unsigned* cnt, unsigned* gen) {
  __syncthreads();
  if (threadIdx.x == 0) {
    __threadfence();  // release all my global writes (agent scope)
    unsigned g = __hip_atomic_load(gen, __ATOMIC_RELAXED, __HIP_MEMORY_SCOPE_AGENT);
    unsigned a = __hip_atomic_fetch_add(cnt, 1u, __ATOMIC_ACQ_REL, __HIP_MEMORY_SCOPE_AGENT);
    if (a == NBLK - 1) {
      __hip_atomic_store(cnt, 0u, __ATOMIC_RELAXED, __HIP_MEMORY_SCOPE_AGENT);
      __hip_atomic_store(gen, g + 1u, __ATOMIC_RELEASE, __HIP_MEMORY_SCOPE_AGENT);
    } else {
      while (__hip_atomic_load(gen, __ATOMIC_ACQUIRE, __HIP_MEMORY_SCOPE_AGENT) == g)
        __builtin_amdgcn_s_sleep(1);
    }
    __threadfence();
  }
  __syncthreads();
}

// ---- converters ----
__global__ void cvt(const float* __restrict__ s, us* __restrict__ d, int n) {
  int i = blockIdx.x * 256 + threadIdx.x;
  if (i < n) d[i] = f2b(s[i]);
}
__global__ void cvt_pad(const float* __restrict__ s, us* __restrict__ d, int C, int Cp, int n) {
  int i = blockIdx.x * 256 + threadIdx.x;
  if (i < n) {
    int r = i / Cp, c = i - r * Cp;
    d[i] = (c < C) ? f2b(s[(size_t)r * C + c]) : (us)0;
  }
}

// ================= tile device functions (prefetched K-loops) =================
// 64x64 GEMM tile: C = act( sum_seg A_seg . W_seg^T + bias ). smem >= 10240 B.
template <int NSEG, bool RELU>
__device__ void tile_gemm(
    int bx, int by,
    const us* A0, const us* W0, int ldw0, int K0,
    const us* A1, const us* W1, int ldw1, int K1,
    const us* A2, const us* W2, int ldw2, int K2,
    const float* bias, us* C, int ldc, char* smemc)
{
  us* As = (us*)smemc; us* Bs = (us*)(smemc + 5120);
  const int tid = threadIdx.x, srow = tid >> 2, scb = (tid & 3) * 8;
  const int lane = tid & 63, w = tid >> 6, l15 = lane & 15, q = lane >> 4;
  const int m0 = by * 64, n0 = bx * 64;
  f32x4 acc[4];
  #pragma unroll
  for (int j = 0; j < 4; ++j) acc[j] = (f32x4){0.f, 0.f, 0.f, 0.f};
  for (int seg = 0; seg < NSEG; ++seg) {
    const us* A = (seg == 0) ? A0 : (seg == 1) ? A1 : A2;
    const us* W = (seg == 0) ? W0 : (seg == 1) ? W1 : W2;
    const int ldw = (seg == 0) ? ldw0 : (seg == 1) ? ldw1 : ldw2;
    const int K   = (seg == 0) ? K0 : (seg == 1) ? K1 : K2;
    const us* ap = A + (size_t)(m0 + srow) * K + scb;
    const us* wp = W + (size_t)(n0 + srow) * ldw + scb;
    uint4 av = *(const uint4*)ap;
    uint4 wv = *(const uint4*)wp;
    for (int k0 = 0; k0 < K; k0 += 32) {
      __syncthreads();
      *(uint4*)&As[srow * 40 + scb] = av;
      *(uint4*)&Bs[srow * 40 + scb] = wv;
      __syncthreads();
      if (k0 + 32 < K) {            // prefetch next k-tile during MFMA
        av = *(const uint4*)(ap + k0 + 32);
        wv = *(const uint4*)(wp + k0 + 32);
      }
      bf16x8 a = *(const bf16x8*)&As[(w * 16 + l15) * 40 + q * 8];
      #pragma unroll
      for (int j = 0; j < 4; ++j) {
        bf16x8 b = *(const bf16x8*)&Bs[(j * 16 + l15) * 40 + q * 8];
        acc[j] = __builtin_amdgcn_mfma_f32_16x16x32_bf16(a, b, acc[j], 0, 0, 0);
      }
    }
  }
  #pragma unroll
  for (int j = 0; j < 4; ++j) {
    const int col = n0 + j * 16 + l15;
    const float bv = bias[col];
    #pragma unroll
    for (int r = 0; r < 4; ++r) {
      const int row = m0 + w * 16 + q * 4 + r;
      float v = acc[j][r] + bv;
      if (RELU) v = fmaxf(v, 0.f);
      C[(size_t)row * ldc + col] = f2b(v);
    }
  }
}

// GRU 64x64 tile. smem >= 20480 B.
template <int NSEGI>
__device__ void tile_gru(
    int bx, int by,
    const us* A0, const us* A1, const us* A2,
    const us* Wih, int ldwih,
    const us* hprev, const us* Whh,
    const float* bih, const float* bhh,
    us* hnew, char* smemc)
{
  us* Asm = (us*)smemc; us* Rs = (us*)(smemc + 5120);
  us* Zs = (us*)(smemc + 10240); us* Ns = (us*)(smemc + 15360);
  const int tid = threadIdx.x, srow = tid >> 2, scb = (tid & 3) * 8;
  const int lane = tid & 63, w = tid >> 6, l15 = lane & 15, q = lane >> 4;
  const int m0 = by * 64, c0 = bx * 64;
  f32x4 aR[4], aZ[4], aI[4], aH[4];
  #pragma unroll
  for (int j = 0; j < 4; ++j) {
    aR[j] = (f32x4){0.f, 0.f, 0.f, 0.f}; aZ[j] = aR[j]; aI[j] = aR[j]; aH[j] = aR[j];
  }
  for (int seg = 0; seg <= NSEGI; ++seg) {
    const bool hseg = (seg == NSEGI);
    const us* A  = hseg ? hprev : ((seg == 0) ? A0 : (seg == 1) ? A1 : A2);
    const us* Wb = hseg ? Whh : Wih;
    const int ldw  = hseg ? Hn : ldwih;
    const int coff = hseg ? 0 : seg * Hn;
    const us* ap = A + (size_t)(m0 + srow) * Hn + scb;
    const us* wr = Wb + (size_t)(c0 + srow) * ldw + coff + scb;
    const us* wz = wr + (size_t)Hn * ldw;
    const us* wn = wz + (size_t)Hn * ldw;
    uint4 av = *(const uint4*)ap;
    uint4 rv = *(const uint4*)wr;
    uint4 zv = *(const uint4*)wz;
    uint4 nv = *(const uint4*)wn;
    for (int k0 = 0; k0 < Hn; k0 += 32) {
      __syncthreads();
      *(uint4*)&Asm[srow * 40 + scb] = av;
      *(uint4*)&Rs[srow * 40 + scb] = rv;
      *(uint4*)&Zs[srow * 40 + scb] = zv;
      *(uint4*)&Ns[srow * 40 + scb] = nv;
      __syncthreads();
      if (k0 + 32 < Hn) {
        av = *(const uint4*)(ap + k0 + 32);
        rv = *(const uint4*)(wr + k0 + 32);
        zv = *(const uint4*)(wz + k0 + 32);
        nv = *(const uint4*)(wn + k0 + 32);
      }
      bf16x8 a = *(const bf16x8*)&Asm[(w * 16 + l15) * 40 + q * 8];
      #pragma unroll
      for (int j = 0; j < 4; ++j) {
        bf16x8 br = *(const bf16x8*)&Rs[(j * 16 + l15) * 40 + q * 8];
        bf16x8 bz = *(const bf16x8*)&Zs[(j * 16 + l15) * 40 + q * 8];
        bf16x8 bn = *(const bf16x8*)&Ns[(j * 16 + l15) * 40 + q * 8];
        aR[j] = __builtin_amdgcn_mfma_f32_16x16x32_bf16(a, br, aR[j], 0, 0, 0);
        aZ[j] = __builtin_amdgcn_mfma_f32_16x16x32_bf16(a, bz, aZ[j], 0, 0, 0);
        if (hseg) aH[j] = __builtin_amdgcn_mfma_f32_16x16x32_bf16(a, bn, aH[j], 0, 0, 0);
        else      aI[j] = __builtin_amdgcn_mfma_f32_16x16x32_bf16(a, bn, aI[j], 0, 0, 0);
      }
    }
  }
  #pragma unroll
  for (int j = 0; j < 4; ++j) {
    const int c = c0 + j * 16 + l15;
    const float bR = bih[c] + bhh[c];
    const float bZ = bih[Hn + c] + bhh[Hn + c];
    const float bI = bih[2 * Hn + c];
    const float bH = bhh[2 * Hn + c];
    #pragma unroll
    for (int r = 0; r < 4; ++r) {
      const int m = m0 + w * 16 + q * 4 + r;
      const float h = b2f(hprev[(size_t)m * Hn + c]);
      const float rg = sigmf(aR[j][r] + bR);
      const float zg = sigmf(aZ[j][r] + bZ);
      const float ng = tanhf(aI[j][r] + bI + rg * (aH[j][r] + bH));
      hnew[(size_t)m * Hn + c] = f2b((1.0f - zg) * ng + zg * h);
    }
  }
}

// decoder GEMM tile + fused BCE reduction. smem >= 10256 B.
__device__ void tile_nll(
    int bx, int by,
    const us* dec, const us* dmW, const float* dmb, const float* xt,
    float* nll, char* smemc)
{
  us* As = (us*)smemc; us* Bs = (us*)(smemc + 5120);
  float* red = (float*)(smemc + 10240);
  const int tid = threadIdx.x, srow = tid >> 2, scb = (tid & 3) * 8;
  const int lane = tid & 63, w = tid >> 6, l15 = lane & 15, q = lane >> 4;
  const int m0 = by * 64, n0 = bx * 64;
  f32x4 acc[4];
  #pragma unroll
  for (int j = 0; j < 4; ++j) acc[j] = (f32x4){0.f, 0.f, 0.f, 0.f};
  const int wrow = (n0 + srow < Xn) ? (n0 + srow) : (Xn - 1);
  const us* ap = dec + (size_t)(m0 + srow) * Hn + scb;
  const us* wp = dmW + (size_t)wrow * Hn + scb;
  uint4 av = *(const uint4*)ap;
  uint4 wv = *(const uint4*)wp;
  for (int k0 = 0; k0 < Hn; k0 += 32) {
    __syncthreads();
    *(uint4*)&As[srow * 40 + scb] = av;
    *(uint4*)&Bs[srow * 40 + scb] = wv;
    __syncthreads();
    if (k0 + 32 < Hn) {
      av = *(const uint4*)(ap + k0 + 32);
      wv = *(const uint4*)(wp + k0 + 32);
    }
    bf16x8 a = *(const bf16x8*)&As[(w * 16 + l15) * 40 + q * 8];
    #pragma unroll
    for (int j = 0; j < 4; ++j) {
      bf16x8 b = *(const bf16x8*)&Bs[(j * 16 + l15) * 40 + q * 8];
      acc[j] = __builtin_amdgcn_mfma_f32_16x16x32_bf16(a, b, acc[j], 0, 0, 0);
    }
  }
  float sum = 0.0f;
  #pragma unroll
  for (int j = 0; j < 4; ++j) {
    const int n = n0 + j * 16 + l15;
    if (n < Xn) {
      const float bv = dmb[n];
      #pragma unroll
      for (int r = 0; r < 4; ++r) {
        const int m = m0 + w * 16 + q * 4 + r;
        const float a = acc[j][r] + bv;
        const float xv = xt[(size_t)m * Xn + n];
        sum += splusf(-a) + (1.0f - xv) * a;
      }
    }
  }
  const float s = block_sum(sum, red);
  if (tid == 0) atomicAdd(nll, s);
}

// dual-head stats tile (64 rows). smem >= 15376 B.
// MODE 0: mu->o_pm, sd->o_ps (fp32). MODE 1: f=eps*sd+mu->o0b, f_kld->kacc.
// MODE 2: zt=eps*sd+mu->o0b, z_kld vs (pm_in,ps_in)->kacc.
template <int MODE>
__device__ void stat_dual(int vb,
    const us* Ain, const us* Wm, const float* bm, const us* Ws, const float* bs,
    const float* eps, const float* pm_in, const float* ps_in,
    us* o0b, float* o_pm, float* o_ps, float* kacc, char* smemc)
{
  us* As = (us*)smemc; us* Ms = (us*)(smemc + 5120); us* Ss = (us*)(smemc + 10240);
  float* red = (float*)(smemc + 15360);
  const int tid = threadIdx.x, srow = tid >> 2, scb = (tid & 3) * 8;
  const int lane = tid & 63, w = tid >> 6, l15 = lane & 15, q = lane >> 4;
  const int m0 = vb * 64;
  f32x4 am[4], as_[4];
  #pragma unroll
  for (int j = 0; j < 4; ++j) { am[j] = (f32x4){0.f, 0.f, 0.f, 0.f}; as_[j] = am[j]; }
  const us* ap = Ain + (size_t)(m0 + srow) * Hn + scb;
  const us* mp = Wm + (size_t)srow * Hn + scb;
  const us* sp = Ws + (size_t)srow * Hn + scb;
  uint4 av = *(const uint4*)ap;
  uint4 mv = *(const uint4*)mp;
  uint4 sv = *(const uint4*)sp;
  for (int k0 = 0; k0 < Hn; k0 += 32) {
    __syncthreads();
    *(uint4*)&As[srow * 40 + scb] = av;
    *(uint4*)&Ms[srow * 40 + scb] = mv;
    *(uint4*)&Ss[srow * 40 + scb] = sv;
    __syncthreads();
    if (k0 + 32 < Hn) {
      av = *(const uint4*)(ap + k0 + 32);
      mv = *(const uint4*)(mp + k0 + 32);
      sv = *(const uint4*)(sp + k0 + 32);
    }
    bf16x8 a = *(const bf16x8*)&As[(w * 16 + l15) * 40 + q * 8];
    #pragma unroll
    for (int j = 0; j < 4; ++j) {
      bf16x8 b0 = *(const bf16x8*)&Ms[(j * 16 + l15) * 40 + q * 8];
      bf16x8 b1 = *(const bf16x8*)&Ss[(j * 16 + l15) * 40 + q * 8];
      am[j]  = __builtin_amdgcn_mfma_f32_16x16x32_bf16(a, b0, am[j], 0, 0, 0);
      as_[j] = __builtin_amdgcn_mfma_f32_16x16x32_bf16(a, b1, as_[j], 0, 0, 0);
    }
  }
  float kld = 0.0f;
  #pragma unroll
  for (int j = 0; j < 4; ++j) {
    const int c = j * 16 + l15;
    const float bmv = bm[c], bsv = bs[c];
    #pragma unroll
    for (int r = 0; r < 4; ++r) {
      const int m = m0 + w * 16 + q * 4 + r;
      const float mu = am[j][r] + bmv;
      const float sd = splusf(as_[j][r] + bsv);
      if (MODE == 0) {
        o_pm[(size_t)m * Zn + c] = mu;
        o_ps[(size_t)m * Zn + c] = sd;
      } else {
        o0b[(size_t)m * Zn + c] = f2b(eps[(size_t)m * Zn + c] * sd + mu);
        if (MODE == 1) {
          kld += mu * mu + sd * sd - 2.0f * __logf(sd) - 1.0f;
        } else {
          const float pm = pm_in[(size_t)m * Zn + c];
          const float ps = ps_in[(size_t)m * Zn + c];
          const float dd = (mu - pm) / ps;
          const float rr = sd / ps;
          kld += dd * dd + rr * rr - 2.0f * __logf(rr) - 1.0f;
        }
      }
    }
  }
  if (MODE != 0) {
    const float s = block_sum(kld, red);
    if (tid == 0) atomicAdd(kacc, 0.5f * s);
  }
}

// ---- phase-A standalone GEMM ----
__global__ __launch_bounds__(256) void k_gemm1(
    const us* A0, const us* W0, int ldw0, int K0, const float* bias, us* C, int ldc)
{
  __shared__ alignas(16) char sm[10240];
  tile_gemm<1, true>(blockIdx.x, blockIdx.y, A0, W0, ldw0, K0,
                     nullptr, nullptr, 0, 0, nullptr, nullptr, 0, 0, bias, C, ldc, sm);
}

// ================= persistent kernel =================
struct Params {
  const float *x, *eps_f, *eps_z;
  const float *pzb, *pfb, *rbih, *rbhh, *zpb, *zpmb, *zpsb,
              *febih, *febhh, *femb, *fesb, *zeb1, *zeb2, *zemb, *zesb,
              *db1, *db2, *dmb;
  const us *pzW, *pfW, *rWih, *rWhh, *zpW, *zpmW, *zpsW, *feWih, *feWhh,
           *femW, *fesW, *zeW1, *zeW2, *zemW, *zesW, *dW1, *dW2, *dmW;
  const us *phi_x;
  us *fh_a, *fh_b, *h_a, *h_b, *fbuf, *phi_f, *zp, *zepre, *ze, *zt, *phiz, *dtmp, *dec;
  float *zpm, *zps, *out;
  unsigned *bar_cnt, *bar_gen;
};

__global__ __launch_bounds__(256) void persist(Params p) {
  __shared__ alignas(16) char sm[20992];
  const int b = blockIdx.x;

  // ---- Phase B: f-encoder GRU over T ----
  {
    us* fc = p.fh_a; us* fn = p.fh_b;
    for (int t = 0; t < Tn; ++t) {
      if (b < 64)
        tile_gru<1>(b & 7, b >> 3, p.phi_x + (size_t)t * Bn * Hn, nullptr, nullptr,
                    p.feWih, Hn, fc, p.feWhh, p.febih, p.febhh, fn, sm);
      gridbar(p.bar_cnt, p.bar_gen);
      us* sw = fc; fc = fn; fn = sw;
    }
  }
  const us* fh = p.fh_a;  // Tn even -> final hidden back in fh_a

  // ---- Phase C: f stats (8 tiles) ----
  if (b < 8)
    stat_dual<1>(b, fh, p.femW, p.femb, p.fesW, p.fesb, p.eps_f,
                 nullptr, nullptr, p.fbuf, nullptr, nullptr, p.out + 0, sm);
  gridbar(p.bar_cnt, p.bar_gen);

  // ---- Prologue A1(0): zp(64) | zepre(64) | phi_f(64) ----
  if (b < 64)
    tile_gemm<1, true>(b & 7, b >> 3, p.h_a, p.zpW, Hn, Hn,
                       nullptr, nullptr, 0, 0, nullptr, nullptr, 0, 0,
                       p.zpb, p.zp, Hn, sm);
  else if (b < 128)
    tile_gemm<2, true>((b - 64) & 7, (b - 64) >> 3,
                       p.phi_x, p.zeW1, 1024, Hn, p.h_a, p.zeW1 + 512, 1024, Hn,
                       nullptr, nullptr, 0, 0, p.zeb1, p.zepre, Hn, sm);
  else
    tile_gemm<1, true>((b - 128) & 7, (b - 128) >> 3, p.fbuf, p.pfW, Fn, Fn,
                       nullptr, nullptr, 0, 0, nullptr, nullptr, 0, 0,
                       p.pfb, p.phi_f, Hn, sm);
  gridbar(p.bar_cnt, p.bar_gen);

  // ---- Prologue A2(0): ze(64) | zpstat(8) ----
  if (b < 64)
    tile_gemm<1, true>(b & 7, b >> 3, p.zepre, p.zeW2, Hn, Hn,
                       nullptr, nullptr, 0, 0, nullptr, nullptr, 0, 0,
                       p.zeb2, p.ze, Hn, sm);
  else if (b < 72)
    stat_dual<0>(b - 64, p.zp, p.zpmW, p.zpmb, p.zpsW, p.zpsb,
                 nullptr, nullptr, nullptr, nullptr, p.zpm, p.zps, nullptr, sm);
  gridbar(p.bar_cnt, p.bar_gen);

  // ---- Phase D main loop ----
  for (int t = 0; t < Tn; ++t) {
    const us* hcur = (t & 1) ? p.h_b : p.h_a;
    us* hnext      = (t & 1) ? p.h_a : p.h_b;
    const bool pip = (t < Tn - 1);

    // A3: enc stats -> zt, z_kld
    if (b < 8)
      stat_dual<2>(b, p.ze, p.zemW, p.zemb, p.zesW, p.zesb,
                   p.eps_z + (size_t)t * Bn * Zn, p.zpm, p.zps,
                   p.zt, nullptr, nullptr, p.out + 1, sm);
    gridbar(p.bar_cnt, p.bar_gen);

    // A4: phiz = relu(zt@pzW^T + pzb), K=64
    if (b < 64)
      tile_gemm<1, true>(b & 7, b >> 3, p.zt, p.pzW, Zn, Zn,
                         nullptr, nullptr, 0, 0, nullptr, nullptr, 0, 0,
                         p.pzb, p.phiz, Hn, sm);
    gridbar(p.bar_cnt, p.bar_gen);

    // A5: gru(64) | dtmp(64)
    if (b < 64)
      tile_gru<3>(b & 7, b >> 3, p.phi_x + (size_t)t * Bn * Hn, p.phiz, p.phi_f,
                  p.rWih, 1536, hcur, p.rWhh, p.rbih, p.rbhh, hnext, sm);
    else if (b < 128)
      tile_gemm<3, true>((b - 64) & 7, (b - 64) >> 3,
                         p.phiz, p.dW1, 1536, Hn, p.phi_f, p.dW1 + 512, 1536, Hn,
                         hcur, p.dW1 + 1024, 1536, Hn, p.db1, p.dtmp, Hn, sm);
    gridbar(p.bar_cnt, p.bar_gen);

    // A6: dec(64) | zp'(64) | zepre'(64)   (primed stages use hnext)
    if (b < 64)
      tile_gemm<1, true>(b & 7, b >> 3, p.dtmp, p.dW2, Hn, Hn,
                         nullptr, nullptr, 0, 0, nullptr, nullptr, 0, 0,
                         p.db2, p.dec, Hn, sm);
    else if (pip && b < 128)
      tile_gemm<1, true>((b - 64) & 7, (b - 64) >> 3, hnext, p.zpW, Hn, Hn,
                         nullptr, nullptr, 0, 0, nullptr, nullptr, 0, 0,
                         p.zpb, p.zp, Hn, sm);
    else if (pip && b < 192)
      tile_gemm<2, true>((b - 128) & 7, (b - 128) >> 3,
                         p.phi_x + (size_t)(t + 1) * Bn * Hn, p.zeW1, 1024, Hn,
                         hnext, p.zeW1 + 512, 1024, Hn, nullptr, nullptr, 0, 0,
                         p.zeb1, p.zepre, Hn, sm);
    gridbar(p.bar_cnt, p.bar_gen);

    // A7: nll(104) | ze'(64) | zpstat'(8)
    if (b < 104)
      tile_nll(b % 13, b / 13, p.dec, p.dmW, p.dmb,
               p.x + (size_t)t * Bn * Xn, p.out + 2, sm);
    else if (pip && b < 168)
      tile_gemm<1, true>((b - 104) & 7, (b - 104) >> 3, p.zepre, p.zeW2, Hn, Hn,
                         nullptr, nullptr, 0, 0, nullptr, nullptr, 0, 0,
                         p.zeb2, p.ze, Hn, sm);
    else if (pip && b < 176)
      stat_dual<0>(b - 168, p.zp, p.zpmW, p.zpmb, p.zpsW, p.zpsb,
                   nullptr, nullptr, nullptr, nullptr, p.zpm, p.zps, nullptr, sm);
    gridbar(p.bar_cnt, p.bar_gen);
  }
}

} // anonymous namespace

extern "C" void kernel_launch(void* const* d_in, const int* in_sizes, int n_in,
                              void* d_out, int out_size, void* d_ws, size_t ws_size,
                              hipStream_t stream)
{
  (void)in_sizes; (void)n_in; (void)out_size;
  const float* x     = (const float*)d_in[0];
  const float* eps_f = (const float*)d_in[1];
  const float* eps_z = (const float*)d_in[2];
  const float* pxW1  = (const float*)d_in[3];
  const float* pxb1  = (const float*)d_in[4];
  const float* pxW2  = (const float*)d_in[5];
  const float* pxb2  = (const float*)d_in[6];
  const float* pzW   = (const float*)d_in[7];
  const float* pzb   = (const float*)d_in[8];
  const float* pfW   = (const float*)d_in[9];
  const float* pfb   = (const float*)d_in[10];
  const float* rWih  = (const float*)d_in[11];
  const float* rWhh  = (const float*)d_in[12];
  const float* rbih  = (const float*)d_in[13];
  const float* rbhh  = (const float*)d_in[14];
  const float* zpW   = (const float*)d_in[15];
  const float* zpb   = (const float*)d_in[16];
  const float* zpmW  = (const float*)d_in[17];
  const float* zpmb  = (const float*)d_in[18];
  const float* zpsW  = (const float*)d_in[19];
  const float* zpsb  = (const float*)d_in[20];
  const float* feWih = (const float*)d_in[21];
  const float* feWhh = (const float*)d_in[22];
  const float* febih = (const float*)d_in[23];
  const float* febhh = (const float*)d_in[24];
  const float* femW  = (const float*)d_in[25];
  const float* femb  = (const float*)d_in[26];
  const float* fesW  = (const float*)d_in[27];
  const float* fesb  = (const float*)d_in[28];
  const float* zeW1  = (const float*)d_in[29];
  const float* zeb1  = (const float*)d_in[30];
  const float* zeW2  = (const float*)d_in[31];
  const float* zeb2  = (const float*)d_in[32];
  const float* zemW  = (const float*)d_in[33];
  const float* zemb  = (const float*)d_in[34];
  const float* zesW  = (const float*)d_in[35];
  const float* zesb  = (const float*)d_in[36];
  const float* dW1   = (const float*)d_in[37];
  const float* db1   = (const float*)d_in[38];
  const float* dW2   = (const float*)d_in[39];
  const float* db2   = (const float*)d_in[40];
  const float* dmW   = (const float*)d_in[41];
  const float* dmb   = (const float*)d_in[42];
  float* out = (float*)d_out;

  char* base = (char*)d_ws;
  size_t off = 0;
  auto ab = [&](size_t bytes) -> void* {
    void* p = base + off;
    off += (bytes + 255) & ~(size_t)255;
    return p;
  };

  // barrier state first (stable address)
  unsigned* bar = (unsigned*)ab(256);

  // bf16 weights
  us* b_pxW1  = (us*)ab((size_t)512 * XnP * 2);
  us* b_pxW2  = (us*)ab((size_t)512 * 512 * 2);
  us* b_pzW   = (us*)ab((size_t)512 * 64 * 2);
  us* b_pfW   = (us*)ab((size_t)512 * 64 * 2);
  us* b_rWih  = (us*)ab((size_t)1536 * 1536 * 2);
  us* b_rWhh  = (us*)ab((size_t)1536 * 512 * 2);
  us* b_zpW   = (us*)ab((size_t)512 * 512 * 2);
  us* b_zpmW  = (us*)ab((size_t)64 * 512 * 2);
  us* b_zpsW  = (us*)ab((size_t)64 * 512 * 2);
  us* b_feWih = (us*)ab((size_t)1536 * 512 * 2);
  us* b_feWhh = (us*)ab((size_t)1536 * 512 * 2);
  us* b_femW  = (us*)ab((size_t)64 * 512 * 2);
  us* b_fesW  = (us*)ab((size_t)64 * 512 * 2);
  us* b_zeW1  = (us*)ab((size_t)512 * 1024 * 2);
  us* b_zeW2  = (us*)ab((size_t)512 * 512 * 2);
  us* b_zemW  = (us*)ab((size_t)64 * 512 * 2);
  us* b_zesW  = (us*)ab((size_t)64 * 512 * 2);
  us* b_dW1   = (us*)ab((size_t)512 * 1536 * 2);
  us* b_dW2   = (us*)ab((size_t)512 * 512 * 2);
  us* b_dmW   = (us*)ab((size_t)Xn * 512 * 2);

  // activations
  us* phi_x = (us*)ab((size_t)Tn * Bn * Hn * 2);
  us* fh_a  = (us*)ab((size_t)Bn * Hn * 2);
  us* h_a   = (us*)ab((size_t)Bn * Hn * 2);   // adjacent to fh_a (one memset)
  us* fh_b  = (us*)ab((size_t)Bn * Hn * 2);
  us* h_b   = (us*)ab((size_t)Bn * Hn * 2);
  us* fbuf  = (us*)ab((size_t)Bn * Fn * 2);
  us* phi_f = (us*)ab((size_t)Bn * Hn * 2);
  us* zp    = (us*)ab((size_t)Bn * Hn * 2);
  us* zepre = (us*)ab((size_t)Bn * Hn * 2);
  us* ze    = (us*)ab((size_t)Bn * Hn * 2);
  us* zt    = (us*)ab((size_t)Bn * Zn * 2);
  us* phiz  = (us*)ab((size_t)Bn * Hn * 2);
  us* dtmp  = (us*)ab((size_t)Bn * Hn * 2);
  us* dec   = (us*)ab((size_t)Bn * Hn * 2);
  float* zpm = (float*)ab((size_t)Bn * Zn * 4);
  float* zps = (float*)ab((size_t)Bn * Zn * 4);

  int CH = 16;
  while (CH > 1 && off + (size_t)CH * (Bn * XnP + Bn * Hn) * 2 + 4096 > ws_size) CH >>= 1;
  us* xch  = (us*)ab((size_t)CH * Bn * XnP * 2);
  us* tmpb = (us*)ab((size_t)CH * Bn * Hn * 2);

  hipMemsetAsync(d_out, 0, 3 * sizeof(float), stream);
  hipMemsetAsync(bar, 0, 256, stream);
  hipMemsetAsync(fh_a, 0, 2 * (size_t)Bn * Hn * 2, stream);  // fh_a + h_a

  const dim3 blk(256);
  auto CVT = [&](const float* s, us* d, size_t n) {
    cvt<<<dim3((unsigned)((n + 255) / 256)), blk, 0, stream>>>(s, d, (int)n);
  };

  {
    const size_t n = (size_t)512 * XnP;
    cvt_pad<<<dim3((unsigned)((n + 255) / 256)), blk, 0, stream>>>(pxW1, b_pxW1, Xn, XnP, (int)n);
  }
  CVT(pxW2, b_pxW2, (size_t)512 * 512);
  CVT(pzW, b_pzW, (size_t)512 * 64);
  CVT(pfW, b_pfW, (size_t)512 * 64);
  CVT(rWih, b_rWih, (size_t)1536 * 1536);
  CVT(rWhh, b_rWhh, (size_t)1536 * 512);
  CVT(zpW, b_zpW, (size_t)512 * 512);
  CVT(zpmW, b_zpmW, (size_t)64 * 512);
  CVT(zpsW, b_zpsW, (size_t)64 * 512);
  CVT(feWih, b_feWih, (size_t)1536 * 512);
  CVT(feWhh, b_feWhh, (size_t)1536 * 512);
  CVT(femW, b_femW, (size_t)64 * 512);
  CVT(fesW, b_fesW, (size_t)64 * 512);
  CVT(zeW1, b_zeW1, (size_t)512 * 1024);
  CVT(zeW2, b_zeW2, (size_t)512 * 512);
  CVT(zemW, b_zemW, (size_t)64 * 512);
  CVT(zesW, b_zesW, (size_t)64 * 512);
  CVT(dW1, b_dW1, (size_t)512 * 1536);
  CVT(dW2, b_dW2, (size_t)512 * 512);
  CVT(dmW, b_dmW, (size_t)Xn * 512);

  // Phase A: phi_x (parallel, ordinary launches)
  for (int c = 0; c < Tn / CH; ++c) {
    const size_t nx = (size_t)CH * Bn * XnP;
    cvt_pad<<<dim3((unsigned)((nx + 255) / 256)), blk, 0, stream>>>(
        x + (size_t)c * CH * Bn * Xn, xch, Xn, XnP, (int)nx);
    const dim3 gA(8, CH * Bn / 64);
    k_gemm1<<<gA, blk, 0, stream>>>(xch, b_pxW1, XnP, XnP, pxb1, tmpb, Hn);
    k_gemm1<<<gA, blk, 0, stream>>>(tmpb, b_pxW2, Hn, Hn, pxb2,
                                    phi_x + (size_t)c * CH * Bn * Hn, Hn);
  }

  // Phases B + C + D: one persistent kernel with grid barriers
  Params p;
  p.x = x; p.eps_f = eps_f; p.eps_z = eps_z;
  p.pzb = pzb; p.pfb = pfb; p.rbih = rbih; p.rbhh = rbhh;
  p.zpb = zpb; p.zpmb = zpmb; p.zpsb = zpsb;
  p.febih = febih; p.febhh = febhh; p.femb = femb; p.fesb = fesb;
  p.zeb1 = zeb1; p.zeb2 = zeb2; p.zemb = zemb; p.zesb = zesb;
  p.db1 = db1; p.db2 = db2; p.dmb = dmb;
  p.pzW = b_pzW; p.pfW = b_pfW; p.rWih = b_rWih; p.rWhh = b_rWhh;
  p.zpW = b_zpW; p.zpmW = b_zpmW; p.zpsW = b_zpsW;
  p.feWih = b_feWih; p.feWhh = b_feWhh; p.femW = b_femW; p.fesW = b_fesW;
  p.zeW1 = b_zeW1; p.zeW2 = b_zeW2; p.zemW = b_zemW; p.zesW = b_zesW;
  p.dW1 = b_dW1; p.dW2 = b_dW2; p.dmW = b_dmW;
  p.phi_x = phi_x;
  p.fh_a = fh_a; p.fh_b = fh_b; p.h_a = h_a; p.h_b = h_b;
  p.fbuf = fbuf; p.phi_f = phi_f; p.zp = zp; p.zepre = zepre; p.ze = ze;
  p.zt = zt; p.phiz = phiz; p.dtmp = dtmp; p.dec = dec;
  p.zpm = zpm; p.zps = zps; p.out = out;
  p.bar_cnt = bar; p.bar_gen = (unsigned*)((char*)bar + 128);

  persist<<<dim3(NBLK), blk, 0, stream>>>(p);
}

// Round 5
// 6581.124 us; speedup vs baseline: 3.6866x; 3.6866x over previous
//
#include <hip/hip_runtime.h>
#include <cmath>

namespace {

constexpr int Tn = 64;
constexpr int Bn = 512;
constexpr int Xn = 784;
constexpr int XnP = 800;
constexpr int Fn = 64;
constexpr int Zn = 64;
constexpr int Hn = 512;

typedef unsigned short us;
typedef __attribute__((ext_vector_type(8))) short bf16x8;
typedef __attribute__((ext_vector_type(4))) float f32x4;

__device__ __forceinline__ us f2b(float v) {
  unsigned int u = __float_as_uint(v);
  return (us)((u + 0x7FFFu + ((u >> 16) & 1u)) >> 16);
}
__device__ __forceinline__ float b2f(us u) { return __uint_as_float(((unsigned int)u) << 16); }
__device__ __forceinline__ float sigmf(float v) { return 1.0f / (1.0f + __expf(-v)); }
__device__ __forceinline__ float splusf(float v) {
  return v > 0.0f ? (v + log1pf(__expf(-v))) : log1pf(__expf(v));
}
__device__ __forceinline__ float block_sum(float v, float* red) {
  #pragma unroll
  for (int off = 32; off > 0; off >>= 1) v += __shfl_down(v, off, 64);
  if ((threadIdx.x & 63) == 0) red[threadIdx.x >> 6] = v;
  __syncthreads();
  float s = 0.0f;
  if (threadIdx.x == 0) s = red[0] + red[1] + red[2] + red[3];
  return s;
}

// ---- converters ----
__global__ void cvt(const float* __restrict__ s, us* __restrict__ d, int n) {
  int i = blockIdx.x * 256 + threadIdx.x;
  if (i < n) d[i] = f2b(s[i]);
}
__global__ void cvt_pad(const float* __restrict__ s, us* __restrict__ d, int C, int Cp, int n) {
  int i = blockIdx.x * 256 + threadIdx.x;
  if (i < n) {
    int r = i / Cp, c = i - r * Cp;
    d[i] = (c < C) ? f2b(s[(size_t)r * C + c]) : (us)0;
  }
}

// ================= tile device functions =================
// 64x64 GEMM tile with optional fp32 accumulator init, fp32/bf16 out, bias, relu.
// smem >= 10240 B.
template <int NSEG, bool RELU, bool F32OUT, bool HASINIT, bool HASBIAS>
__device__ void tile_gemmx(
    int bx, int by,
    const us* A0, const us* W0, int ldw0, int K0,
    const us* A1, const us* W1, int ldw1, int K1,
    const float* initC, int ldi, const float* bias,
    void* Cout, int ldc, char* smemc)
{
  us* As = (us*)smemc; us* Bs = (us*)(smemc + 5120);
  const int tid = threadIdx.x, srow = tid >> 2, scb = (tid & 3) * 8;
  const int lane = tid & 63, w = tid >> 6, l15 = lane & 15, q = lane >> 4;
  const int m0 = by * 64, n0 = bx * 64;
  f32x4 acc[4];
  if (HASINIT) {
    #pragma unroll
    for (int j = 0; j < 4; ++j)
      #pragma unroll
      for (int r = 0; r < 4; ++r)
        acc[j][r] = initC[(size_t)(m0 + w * 16 + q * 4 + r) * ldi + n0 + j * 16 + l15];
  } else {
    #pragma unroll
    for (int j = 0; j < 4; ++j) acc[j] = (f32x4){0.f, 0.f, 0.f, 0.f};
  }
  #pragma unroll
  for (int seg = 0; seg < NSEG; ++seg) {
    const us* A = (seg == 0) ? A0 : A1;
    const us* W = (seg == 0) ? W0 : W1;
    const int ldw = (seg == 0) ? ldw0 : ldw1;
    const int K   = (seg == 0) ? K0 : K1;
    const us* ap = A + (size_t)(m0 + srow) * K + scb;
    const us* wp = W + (size_t)(n0 + srow) * ldw + scb;
    uint4 av = *(const uint4*)ap;
    uint4 wv = *(const uint4*)wp;
    for (int k0 = 0; k0 < K; k0 += 32) {
      __syncthreads();
      *(uint4*)&As[srow * 40 + scb] = av;
      *(uint4*)&Bs[srow * 40 + scb] = wv;
      __syncthreads();
      if (k0 + 32 < K) {
        av = *(const uint4*)(ap + k0 + 32);
        wv = *(const uint4*)(wp + k0 + 32);
      }
      bf16x8 a = *(const bf16x8*)&As[(w * 16 + l15) * 40 + q * 8];
      #pragma unroll
      for (int j = 0; j < 4; ++j) {
        bf16x8 b = *(const bf16x8*)&Bs[(j * 16 + l15) * 40 + q * 8];
        acc[j] = __builtin_amdgcn_mfma_f32_16x16x32_bf16(a, b, acc[j], 0, 0, 0);
      }
    }
  }
  #pragma unroll
  for (int j = 0; j < 4; ++j) {
    const int col = n0 + j * 16 + l15;
    const float bv = HASBIAS ? bias[col] : 0.f;
    #pragma unroll
    for (int r = 0; r < 4; ++r) {
      const int row = m0 + w * 16 + q * 4 + r;
      float v = acc[j][r] + bv;
      if (RELU) v = fmaxf(v, 0.f);
      if (F32OUT) ((float*)Cout)[(size_t)row * ldc + col] = v;
      else        ((us*)Cout)[(size_t)row * ldc + col] = f2b(v);
    }
  }
}

// Phase-B GRU tile (2 segs: gi = A0@Wih^T, gh = h@Whh^T). smem >= 20480 B.
__device__ void tile_gru_fe(
    int bx, int by,
    const us* A0, const us* Wih,
    const us* hprev, const us* Whh,
    const float* bih, const float* bhh,
    us* hnew, char* smemc)
{
  us* Asm = (us*)smemc; us* Rs = (us*)(smemc + 5120);
  us* Zs = (us*)(smemc + 10240); us* Ns = (us*)(smemc + 15360);
  const int tid = threadIdx.x, srow = tid >> 2, scb = (tid & 3) * 8;
  const int lane = tid & 63, w = tid >> 6, l15 = lane & 15, q = lane >> 4;
  const int m0 = by * 64, c0 = bx * 64;
  f32x4 aR[4], aZ[4], aI[4], aH[4];
  #pragma unroll
  for (int j = 0; j < 4; ++j) {
    aR[j] = (f32x4){0.f, 0.f, 0.f, 0.f}; aZ[j] = aR[j]; aI[j] = aR[j]; aH[j] = aR[j];
  }
  #pragma unroll
  for (int seg = 0; seg < 2; ++seg) {
    const bool hseg = (seg == 1);
    const us* A  = hseg ? hprev : A0;
    const us* Wb = hseg ? Whh : Wih;
    const us* ap = A + (size_t)(m0 + srow) * Hn + scb;
    const us* wr = Wb + (size_t)(c0 + srow) * Hn + scb;
    const us* wz = wr + (size_t)Hn * Hn;
    const us* wn = wz + (size_t)Hn * Hn;
    uint4 av = *(const uint4*)ap;
    uint4 rv = *(const uint4*)wr;
    uint4 zv = *(const uint4*)wz;
    uint4 nv = *(const uint4*)wn;
    for (int k0 = 0; k0 < Hn; k0 += 32) {
      __syncthreads();
      *(uint4*)&Asm[srow * 40 + scb] = av;
      *(uint4*)&Rs[srow * 40 + scb] = rv;
      *(uint4*)&Zs[srow * 40 + scb] = zv;
      *(uint4*)&Ns[srow * 40 + scb] = nv;
      __syncthreads();
      if (k0 + 32 < Hn) {
        av = *(const uint4*)(ap + k0 + 32);
        rv = *(const uint4*)(wr + k0 + 32);
        zv = *(const uint4*)(wz + k0 + 32);
        nv = *(const uint4*)(wn + k0 + 32);
      }
      bf16x8 a = *(const bf16x8*)&Asm[(w * 16 + l15) * 40 + q * 8];
      #pragma unroll
      for (int j = 0; j < 4; ++j) {
        bf16x8 br = *(const bf16x8*)&Rs[(j * 16 + l15) * 40 + q * 8];
        bf16x8 bz = *(const bf16x8*)&Zs[(j * 16 + l15) * 40 + q * 8];
        bf16x8 bn = *(const bf16x8*)&Ns[(j * 16 + l15) * 40 + q * 8];
        aR[j] = __builtin_amdgcn_mfma_f32_16x16x32_bf16(a, br, aR[j], 0, 0, 0);
        aZ[j] = __builtin_amdgcn_mfma_f32_16x16x32_bf16(a, bz, aZ[j], 0, 0, 0);
        if (hseg) aH[j] = __builtin_amdgcn_mfma_f32_16x16x32_bf16(a, bn, aH[j], 0, 0, 0);
        else      aI[j] = __builtin_amdgcn_mfma_f32_16x16x32_bf16(a, bn, aI[j], 0, 0, 0);
      }
    }
  }
  #pragma unroll
  for (int j = 0; j < 4; ++j) {
    const int c = c0 + j * 16 + l15;
    const float bR = bih[c] + bhh[c];
    const float bZ = bih[Hn + c] + bhh[Hn + c];
    const float bI = bih[2 * Hn + c];
    const float bH = bhh[2 * Hn + c];
    #pragma unroll
    for (int r = 0; r < 4; ++r) {
      const int m = m0 + w * 16 + q * 4 + r;
      const float h = b2f(hprev[(size_t)m * Hn + c]);
      const float rg = sigmf(aR[j][r] + bR);
      const float zg = sigmf(aZ[j][r] + bZ);
      const float ng = tanhf(aI[j][r] + bI + rg * (aH[j][r] + bH));
      hnew[(size_t)m * Hn + c] = f2b((1.0f - zg) * ng + zg * h);
    }
  }
}

// Phase-D GRU final tile: only the phiz segment is a GEMM; gi_px+gi_phif come
// preaccumulated in gipre (fp32), gh comes in ghpre (fp32). smem >= 20480 B.
__device__ void tile_gru_fin(
    int bx, int by,
    const us* phiz, const us* rWih,
    const float* gipre, const float* ghpre,
    const us* hprev,
    const float* bih, const float* bhh,
    us* hnew, char* smemc)
{
  us* Asm = (us*)smemc; us* Rs = (us*)(smemc + 5120);
  us* Zs = (us*)(smemc + 10240); us* Ns = (us*)(smemc + 15360);
  const int tid = threadIdx.x, srow = tid >> 2, scb = (tid & 3) * 8;
  const int lane = tid & 63, w = tid >> 6, l15 = lane & 15, q = lane >> 4;
  const int m0 = by * 64, c0 = bx * 64;
  f32x4 aR[4], aZ[4], aI[4];
  float aH[4][4];
  #pragma unroll
  for (int j = 0; j < 4; ++j) {
    const int c = c0 + j * 16 + l15;
    #pragma unroll
    for (int r = 0; r < 4; ++r) {
      const size_t row = (size_t)(m0 + w * 16 + q * 4 + r) * 1536;
      aR[j][r] = gipre[row + c] + ghpre[row + c];
      aZ[j][r] = gipre[row + 512 + c] + ghpre[row + 512 + c];
      aI[j][r] = gipre[row + 1024 + c];
      aH[j][r] = ghpre[row + 1024 + c];
    }
  }
  // phiz segment: Wih cols [512:1024]
  const us* ap = phiz + (size_t)(m0 + srow) * Hn + scb;
  const us* wr = rWih + (size_t)(c0 + srow) * 1536 + 512 + scb;
  const us* wz = wr + (size_t)512 * 1536;
  const us* wn = wz + (size_t)512 * 1536;
  uint4 av = *(const uint4*)ap;
  uint4 rv = *(const uint4*)wr;
  uint4 zv = *(const uint4*)wz;
  uint4 nv = *(const uint4*)wn;
  for (int k0 = 0; k0 < Hn; k0 += 32) {
    __syncthreads();
    *(uint4*)&Asm[srow * 40 + scb] = av;
    *(uint4*)&Rs[srow * 40 + scb] = rv;
    *(uint4*)&Zs[srow * 40 + scb] = zv;
    *(uint4*)&Ns[srow * 40 + scb] = nv;
    __syncthreads();
    if (k0 + 32 < Hn) {
      av = *(const uint4*)(ap + k0 + 32);
      rv = *(const uint4*)(wr + k0 + 32);
      zv = *(const uint4*)(wz + k0 + 32);
      nv = *(const uint4*)(wn + k0 + 32);
    }
    bf16x8 a = *(const bf16x8*)&Asm[(w * 16 + l15) * 40 + q * 8];
    #pragma unroll
    for (int j = 0; j < 4; ++j) {
      bf16x8 br = *(const bf16x8*)&Rs[(j * 16 + l15) * 40 + q * 8];
      bf16x8 bz = *(const bf16x8*)&Zs[(j * 16 + l15) * 40 + q * 8];
      bf16x8 bn = *(const bf16x8*)&Ns[(j * 16 + l15) * 40 + q * 8];
      aR[j] = __builtin_amdgcn_mfma_f32_16x16x32_bf16(a, br, aR[j], 0, 0, 0);
      aZ[j] = __builtin_amdgcn_mfma_f32_16x16x32_bf16(a, bz, aZ[j], 0, 0, 0);
      aI[j] = __builtin_amdgcn_mfma_f32_16x16x32_bf16(a, bn, aI[j], 0, 0, 0);
    }
  }
  #pragma unroll
  for (int j = 0; j < 4; ++j) {
    const int c = c0 + j * 16 + l15;
    const float bR = bih[c] + bhh[c];
    const float bZ = bih[Hn + c] + bhh[Hn + c];
    const float bI = bih[2 * Hn + c];
    const float bH = bhh[2 * Hn + c];
    #pragma unroll
    for (int r = 0; r < 4; ++r) {
      const int m = m0 + w * 16 + q * 4 + r;
      const float h = b2f(hprev[(size_t)m * Hn + c]);
      const float rg = sigmf(aR[j][r] + bR);
      const float zg = sigmf(aZ[j][r] + bZ);
      const float ng = tanhf(aI[j][r] + bI + rg * (aH[j][r] + bH));
      hnew[(size_t)m * Hn + c] = f2b((1.0f - zg) * ng + zg * h);
    }
  }
}

// decoder GEMM tile + fused BCE reduction. smem >= 10256 B.
__device__ void tile_nll(
    int bx, int by,
    const us* dec, const us* dmW, const float* dmb, const float* xt,
    float* nll, char* smemc)
{
  us* As = (us*)smemc; us* Bs = (us*)(smemc + 5120);
  float* red = (float*)(smemc + 10240);
  const int tid = threadIdx.x, srow = tid >> 2, scb = (tid & 3) * 8;
  const int lane = tid & 63, w = tid >> 6, l15 = lane & 15, q = lane >> 4;
  const int m0 = by * 64, n0 = bx * 64;
  f32x4 acc[4];
  #pragma unroll
  for (int j = 0; j < 4; ++j) acc[j] = (f32x4){0.f, 0.f, 0.f, 0.f};
  const int wrow = (n0 + srow < Xn) ? (n0 + srow) : (Xn - 1);
  const us* ap = dec + (size_t)(m0 + srow) * Hn + scb;
  const us* wp = dmW + (size_t)wrow * Hn + scb;
  uint4 av = *(const uint4*)ap;
  uint4 wv = *(const uint4*)wp;
  for (int k0 = 0; k0 < Hn; k0 += 32) {
    __syncthreads();
    *(uint4*)&As[srow * 40 + scb] = av;
    *(uint4*)&Bs[srow * 40 + scb] = wv;
    __syncthreads();
    if (k0 + 32 < Hn) {
      av = *(const uint4*)(ap + k0 + 32);
      wv = *(const uint4*)(wp + k0 + 32);
    }
    bf16x8 a = *(const bf16x8*)&As[(w * 16 + l15) * 40 + q * 8];
    #pragma unroll
    for (int j = 0; j < 4; ++j) {
      bf16x8 b = *(const bf16x8*)&Bs[(j * 16 + l15) * 40 + q * 8];
      acc[j] = __builtin_amdgcn_mfma_f32_16x16x32_bf16(a, b, acc[j], 0, 0, 0);
    }
  }
  float sum = 0.0f;
  #pragma unroll
  for (int j = 0; j < 4; ++j) {
    const int n = n0 + j * 16 + l15;
    if (n < Xn) {
      const float bv = dmb[n];
      #pragma unroll
      for (int r = 0; r < 4; ++r) {
        const int m = m0 + w * 16 + q * 4 + r;
        const float a = acc[j][r] + bv;
        const float xv = xt[(size_t)m * Xn + n];
        sum += splusf(-a) + (1.0f - xv) * a;
      }
    }
  }
  const float s = block_sum(sum, red);
  if (tid == 0) atomicAdd(nll, s);
}

// dual-head stats tile. smem >= 15376 B.
template <int MODE>
__device__ void stat_dual(int vb,
    const us* Ain, const us* Wm, const float* bm, const us* Ws, const float* bs,
    const float* eps, const float* pm_in, const float* ps_in,
    us* o0b, float* o_pm, float* o_ps, float* kacc, char* smemc)
{
  us* As = (us*)smemc; us* Ms = (us*)(smemc + 5120); us* Ss = (us*)(smemc + 10240);
  float* red = (float*)(smemc + 15360);
  const int tid = threadIdx.x, srow = tid >> 2, scb = (tid & 3) * 8;
  const int lane = tid & 63, w = tid >> 6, l15 = lane & 15, q = lane >> 4;
  const int m0 = vb * 64;
  f32x4 am[4], as_[4];
  #pragma unroll
  for (int j = 0; j < 4; ++j) { am[j] = (f32x4){0.f, 0.f, 0.f, 0.f}; as_[j] = am[j]; }
  const us* ap = Ain + (size_t)(m0 + srow) * Hn + scb;
  const us* mp = Wm + (size_t)srow * Hn + scb;
  const us* sp = Ws + (size_t)srow * Hn + scb;
  uint4 av = *(const uint4*)ap;
  uint4 mv = *(const uint4*)mp;
  uint4 sv = *(const uint4*)sp;
  for (int k0 = 0; k0 < Hn; k0 += 32) {
    __syncthreads();
    *(uint4*)&As[srow * 40 + scb] = av;
    *(uint4*)&Ms[srow * 40 + scb] = mv;
    *(uint4*)&Ss[srow * 40 + scb] = sv;
    __syncthreads();
    if (k0 + 32 < Hn) {
      av = *(const uint4*)(ap + k0 + 32);
      mv = *(const uint4*)(mp + k0 + 32);
      sv = *(const uint4*)(sp + k0 + 32);
    }
    bf16x8 a = *(const bf16x8*)&As[(w * 16 + l15) * 40 + q * 8];
    #pragma unroll
    for (int j = 0; j < 4; ++j) {
      bf16x8 b0 = *(const bf16x8*)&Ms[(j * 16 + l15) * 40 + q * 8];
      bf16x8 b1 = *(const bf16x8*)&Ss[(j * 16 + l15) * 40 + q * 8];
      am[j]  = __builtin_amdgcn_mfma_f32_16x16x32_bf16(a, b0, am[j], 0, 0, 0);
      as_[j] = __builtin_amdgcn_mfma_f32_16x16x32_bf16(a, b1, as_[j], 0, 0, 0);
    }
  }
  float kld = 0.0f;
  #pragma unroll
  for (int j = 0; j < 4; ++j) {
    const int c = j * 16 + l15;
    const float bmv = bm[c], bsv = bs[c];
    #pragma unroll
    for (int r = 0; r < 4; ++r) {
      const int m = m0 + w * 16 + q * 4 + r;
      const float mu = am[j][r] + bmv;
      const float sd = splusf(as_[j][r] + bsv);
      if (MODE == 0) {
        o_pm[(size_t)m * Zn + c] = mu;
        o_ps[(size_t)m * Zn + c] = sd;
      } else {
        o0b[(size_t)m * Zn + c] = f2b(eps[(size_t)m * Zn + c] * sd + mu);
        if (MODE == 1) {
          kld += mu * mu + sd * sd - 2.0f * __logf(sd) - 1.0f;
        } else {
          const float pm = pm_in[(size_t)m * Zn + c];
          const float ps = ps_in[(size_t)m * Zn + c];
          const float dd = (mu - pm) / ps;
          const float rr = sd / ps;
          kld += dd * dd + rr * rr - 2.0f * __logf(rr) - 1.0f;
        }
      }
    }
  }
  if (MODE != 0) {
    const float s = block_sum(kld, red);
    if (tid == 0) atomicAdd(kacc, 0.5f * s);
  }
}

// ================= global kernels =================
__global__ __launch_bounds__(256) void k_gemmA(
    const us* A, const us* W, int ldw, int K, const float* bias, us* C, int ldc)
{
  __shared__ alignas(16) char sm[10240];
  tile_gemmx<1, true, false, false, true>(blockIdx.x, blockIdx.y, A, W, ldw, K,
      nullptr, nullptr, 0, 0, nullptr, 0, bias, C, ldc, sm);
}

__global__ __launch_bounds__(256) void k_gruB(
    const us* A0, const us* Wih, const us* hprev, const us* Whh,
    const float* bih, const float* bhh, us* hnew)
{
  __shared__ alignas(16) char sm[20480];
  tile_gru_fe(blockIdx.x, blockIdx.y, A0, Wih, hprev, Whh, bih, bhh, hnew, sm);
}

__global__ __launch_bounds__(256) void k_statf(
    const us* fh, const us* femW, const float* femb, const us* fesW, const float* fesb,
    const float* eps_f, us* fbuf, float* kacc)
{
  __shared__ alignas(16) char sm[15376];
  stat_dual<1>(blockIdx.x, fh, femW, femb, fesW, fesb, eps_f,
               nullptr, nullptr, fbuf, nullptr, nullptr, kacc, sm);
}

// P2: Cpre_gru = phi_f @ rWih[:,1024:1536]^T (192) | Cpre_dec = phi_f @ dW1[:,512:1024]^T + db1 (64)
__global__ __launch_bounds__(256) void kP2(
    const us* phi_f, const us* rWih, const us* dW1, const float* db1,
    float* Cpre_gru, float* Cpre_dec)
{
  __shared__ alignas(16) char sm[10240];
  const int b = blockIdx.x;
  if (b < 192)
    tile_gemmx<1, false, true, false, false>(b % 24, b / 24, phi_f, rWih + 1024, 1536, Hn,
        nullptr, nullptr, 0, 0, nullptr, 0, nullptr, Cpre_gru, 1536, sm);
  else
    tile_gemmx<1, false, true, false, true>((b - 192) & 7, (b - 192) >> 3,
        phi_f, dW1 + 512, 1536, Hn,
        nullptr, nullptr, 0, 0, nullptr, 0, db1, Cpre_dec, 512, sm);
}

// P3: zp0 (64, from h0=0) | zepre0 (64)
__global__ __launch_bounds__(256) void kP3(
    const us* h0, const us* zpW, const float* zpb, us* zp,
    const us* px0, const us* zeW1, const float* zeb1, us* zepre)
{
  __shared__ alignas(16) char sm[10240];
  const int b = blockIdx.x;
  if (b < 64)
    tile_gemmx<1, true, false, false, true>(b & 7, b >> 3, h0, zpW, Hn, Hn,
        nullptr, nullptr, 0, 0, nullptr, 0, zpb, zp, Hn, sm);
  else
    tile_gemmx<2, true, false, false, true>((b - 64) & 7, (b - 64) >> 3,
        px0, zeW1, 1024, Hn, h0, zeW1 + 512, 1024, Hn,
        nullptr, 0, zeb1, zepre, Hn, sm);
}

// P4: ze0 (64) | zpstat0 (8)
__global__ __launch_bounds__(256) void kP4(
    const us* zepre, const us* zeW2, const float* zeb2, us* ze,
    const us* zp, const us* zpmW, const float* zpmb, const us* zpsW, const float* zpsb,
    float* zpm, float* zps)
{
  __shared__ alignas(16) char sm[15376];
  const int b = blockIdx.x;
  if (b < 64)
    tile_gemmx<1, true, false, false, true>(b & 7, b >> 3, zepre, zeW2, Hn, Hn,
        nullptr, nullptr, 0, 0, nullptr, 0, zeb2, ze, Hn, sm);
  else
    stat_dual<0>(b - 64, zp, zpmW, zpmb, zpsW, zpsb,
                 nullptr, nullptr, nullptr, nullptr, zpm, zps, nullptr, sm);
}

// S1: zestat (8) | gipre = px_t @ rWih[:,0:512]^T + Cpre_gru (192)
__global__ __launch_bounds__(256) void kS1(
    const us* ze, const us* zemW, const float* zemb, const us* zesW, const float* zesb,
    const float* eps_zt, const float* zpm, const float* zps, us* zt, float* kacc,
    const us* px_t, const us* rWih, const float* Cpre_gru, float* gipre)
{
  __shared__ alignas(16) char sm[15376];
  const int b = blockIdx.x;
  if (b < 8)
    stat_dual<2>(b, ze, zemW, zemb, zesW, zesb, eps_zt, zpm, zps,
                 zt, nullptr, nullptr, kacc, sm);
  else {
    const int tb = b - 8;
    tile_gemmx<1, false, true, true, false>(tb % 24, tb / 24, px_t, rWih, 1536, Hn,
        nullptr, nullptr, 0, 0, Cpre_gru, 1536, nullptr, gipre, 1536, sm);
  }
}

// S2: phiz = relu(zt @ pzW^T + pzb) (64)
__global__ __launch_bounds__(256) void kS2(
    const us* zt, const us* pzW, const float* pzb, us* phiz)
{
  __shared__ alignas(16) char sm[10240];
  tile_gemmx<1, true, false, false, true>(blockIdx.x & 7, blockIdx.x >> 3, zt, pzW, Zn, Zn,
      nullptr, nullptr, 0, 0, nullptr, 0, pzb, phiz, Hn, sm);
}

// S3: gru_fin (64) | dtmp = relu(phiz@dW1[:,0:512]^T + dtmph) (64)
__global__ __launch_bounds__(256) void kS3(
    const us* phiz, const us* rWih, const float* gipre, const float* ghpre,
    const us* hprev, const float* rbih, const float* rbhh, us* hnew,
    const us* dW1, const float* dtmph, us* dtmp)
{
  __shared__ alignas(16) char sm[20480];
  const int b = blockIdx.x;
  if (b < 64)
    tile_gru_fin(b & 7, b >> 3, phiz, rWih, gipre, ghpre, hprev, rbih, rbhh, hnew, sm);
  else
    tile_gemmx<1, true, false, true, false>((b - 64) & 7, (b - 64) >> 3, phiz, dW1, 1536, Hn,
        nullptr, nullptr, 0, 0, dtmph, 512, nullptr, dtmp, Hn, sm);
}

// S4: dec (64) | zp' (64) | zepre' (64) | dtmph' (64)
__global__ __launch_bounds__(256) void kS4(
    const us* dtmp, const us* dW2, const float* db2, us* dec,
    const us* hnext, const us* zpW, const float* zpb, us* zp,
    const us* px1, const us* zeW1, const float* zeb1, us* zepre,
    const us* dW1, const float* Cpre_dec, float* dtmph)
{
  __shared__ alignas(16) char sm[10240];
  const int b = blockIdx.x;
  if (b < 64)
    tile_gemmx<1, true, false, false, true>(b & 7, b >> 3, dtmp, dW2, Hn, Hn,
        nullptr, nullptr, 0, 0, nullptr, 0, db2, dec, Hn, sm);
  else if (b < 128)
    tile_gemmx<1, true, false, false, true>((b - 64) & 7, (b - 64) >> 3, hnext, zpW, Hn, Hn,
        nullptr, nullptr, 0, 0, nullptr, 0, zpb, zp, Hn, sm);
  else if (b < 192)
    tile_gemmx<2, true, false, false, true>((b - 128) & 7, (b - 128) >> 3,
        px1, zeW1, 1024, Hn, hnext, zeW1 + 512, 1024, Hn,
        nullptr, 0, zeb1, zepre, Hn, sm);
  else
    tile_gemmx<1, false, true, true, false>((b - 192) & 7, (b - 192) >> 3,
        hnext, dW1 + 1024, 1536, Hn,
        nullptr, nullptr, 0, 0, Cpre_dec, 512, nullptr, dtmph, 512, sm);
}

// S5: nll (104) | ze' (64) | zpstat' (8) | ghpre' = hnext @ rWhh^T (192)
__global__ __launch_bounds__(256) void kS5(
    const us* dec, const us* dmW, const float* dmb, const float* xt, float* nll,
    const us* zepre, const us* zeW2, const float* zeb2, us* ze,
    const us* zp, const us* zpmW, const float* zpmb, const us* zpsW, const float* zpsb,
    float* zpm, float* zps,
    const us* hnext, const us* rWhh, float* ghpre)
{
  __shared__ alignas(16) char sm[15376];
  const int b = blockIdx.x;
  if (b < 104)
    tile_nll(b % 13, b / 13, dec, dmW, dmb, xt, nll, sm);
  else if (b < 168)
    tile_gemmx<1, true, false, false, true>((b - 104) & 7, (b - 104) >> 3, zepre, zeW2, Hn, Hn,
        nullptr, nullptr, 0, 0, nullptr, 0, zeb2, ze, Hn, sm);
  else if (b < 176)
    stat_dual<0>(b - 168, zp, zpmW, zpmb, zpsW, zpsb,
                 nullptr, nullptr, nullptr, nullptr, zpm, zps, nullptr, sm);
  else {
    const int tb = b - 176;
    tile_gemmx<1, false, true, false, false>(tb % 24, tb / 24, hnext, rWhh, Hn, Hn,
        nullptr, nullptr, 0, 0, nullptr, 0, nullptr, ghpre, 1536, sm);
  }
}

} // anonymous namespace

extern "C" void kernel_launch(void* const* d_in, const int* in_sizes, int n_in,
                              void* d_out, int out_size, void* d_ws, size_t ws_size,
                              hipStream_t stream)
{
  (void)in_sizes; (void)n_in; (void)out_size;
  const float* x     = (const float*)d_in[0];
  const float* eps_f = (const float*)d_in[1];
  const float* eps_z = (const float*)d_in[2];
  const float* pxW1  = (const float*)d_in[3];
  const float* pxb1  = (const float*)d_in[4];
  const float* pxW2  = (const float*)d_in[5];
  const float* pxb2  = (const float*)d_in[6];
  const float* pzW   = (const float*)d_in[7];
  const float* pzb   = (const float*)d_in[8];
  const float* pfW   = (const float*)d_in[9];
  const float* pfb   = (const float*)d_in[10];
  const float* rWih  = (const float*)d_in[11];
  const float* rWhh  = (const float*)d_in[12];
  const float* rbih  = (const float*)d_in[13];
  const float* rbhh  = (const float*)d_in[14];
  const float* zpW   = (const float*)d_in[15];
  const float* zpb   = (const float*)d_in[16];
  const float* zpmW  = (const float*)d_in[17];
  const float* zpmb  = (const float*)d_in[18];
  const float* zpsW  = (const float*)d_in[19];
  const float* zpsb  = (const float*)d_in[20];
  const float* feWih = (const float*)d_in[21];
  const float* feWhh = (const float*)d_in[22];
  const float* febih = (const float*)d_in[23];
  const float* febhh = (const float*)d_in[24];
  const float* femW  = (const float*)d_in[25];
  const float* femb  = (const float*)d_in[26];
  const float* fesW  = (const float*)d_in[27];
  const float* fesb  = (const float*)d_in[28];
  const float* zeW1  = (const float*)d_in[29];
  const float* zeb1  = (const float*)d_in[30];
  const float* zeW2  = (const float*)d_in[31];
  const float* zeb2  = (const float*)d_in[32];
  const float* zemW  = (const float*)d_in[33];
  const float* zemb  = (const float*)d_in[34];
  const float* zesW  = (const float*)d_in[35];
  const float* zesb  = (const float*)d_in[36];
  const float* dW1   = (const float*)d_in[37];
  const float* db1   = (const float*)d_in[38];
  const float* dW2   = (const float*)d_in[39];
  const float* db2   = (const float*)d_in[40];
  const float* dmW   = (const float*)d_in[41];
  const float* dmb   = (const float*)d_in[42];
  float* out = (float*)d_out;

  char* base = (char*)d_ws;
  size_t off = 0;
  auto ab = [&](size_t bytes) -> void* {
    void* p = base + off;
    off += (bytes + 255) & ~(size_t)255;
    return p;
  };

  // bf16 weights
  us* b_pxW1  = (us*)ab((size_t)512 * XnP * 2);
  us* b_pxW2  = (us*)ab((size_t)512 * 512 * 2);
  us* b_pzW   = (us*)ab((size_t)512 * 64 * 2);
  us* b_pfW   = (us*)ab((size_t)512 * 64 * 2);
  us* b_rWih  = (us*)ab((size_t)1536 * 1536 * 2);
  us* b_rWhh  = (us*)ab((size_t)1536 * 512 * 2);
  us* b_zpW   = (us*)ab((size_t)512 * 512 * 2);
  us* b_zpmW  = (us*)ab((size_t)64 * 512 * 2);
  us* b_zpsW  = (us*)ab((size_t)64 * 512 * 2);
  us* b_feWih = (us*)ab((size_t)1536 * 512 * 2);
  us* b_feWhh = (us*)ab((size_t)1536 * 512 * 2);
  us* b_femW  = (us*)ab((size_t)64 * 512 * 2);
  us* b_fesW  = (us*)ab((size_t)64 * 512 * 2);
  us* b_zeW1  = (us*)ab((size_t)512 * 1024 * 2);
  us* b_zeW2  = (us*)ab((size_t)512 * 512 * 2);
  us* b_zemW  = (us*)ab((size_t)64 * 512 * 2);
  us* b_zesW  = (us*)ab((size_t)64 * 512 * 2);
  us* b_dW1   = (us*)ab((size_t)512 * 1536 * 2);
  us* b_dW2   = (us*)ab((size_t)512 * 512 * 2);
  us* b_dmW   = (us*)ab((size_t)Xn * 512 * 2);

  // activations
  us* phi_x = (us*)ab((size_t)Tn * Bn * Hn * 2);
  us* fh_a  = (us*)ab((size_t)Bn * Hn * 2);
  us* h_a   = (us*)ab((size_t)Bn * Hn * 2);   // adjacent to fh_a (one memset)
  us* fh_b  = (us*)ab((size_t)Bn * Hn * 2);
  us* h_b   = (us*)ab((size_t)Bn * Hn * 2);
  us* fbuf  = (us*)ab((size_t)Bn * Fn * 2);
  us* phi_f = (us*)ab((size_t)Bn * Hn * 2);
  us* zp    = (us*)ab((size_t)Bn * Hn * 2);
  us* zepre = (us*)ab((size_t)Bn * Hn * 2);
  us* ze    = (us*)ab((size_t)Bn * Hn * 2);
  us* zt    = (us*)ab((size_t)Bn * Zn * 2);
  us* phiz  = (us*)ab((size_t)Bn * Hn * 2);
  us* dtmp  = (us*)ab((size_t)Bn * Hn * 2);
  us* dec   = (us*)ab((size_t)Bn * Hn * 2);
  float* zpm = (float*)ab((size_t)Bn * Zn * 4);
  float* zps = (float*)ab((size_t)Bn * Zn * 4);
  // fp32 precompute / hoist buffers
  float* Cpre_gru = (float*)ab((size_t)Bn * 1536 * 4);
  float* Cpre_dec = (float*)ab((size_t)Bn * 512 * 4);
  float* gipre    = (float*)ab((size_t)Bn * 1536 * 4);
  float* ghpre    = (float*)ab((size_t)Bn * 1536 * 4);
  float* dtmph    = (float*)ab((size_t)Bn * 512 * 4);

  int CH = 16;
  while (CH > 1 && off + (size_t)CH * (Bn * XnP + Bn * Hn) * 2 + 4096 > ws_size) CH >>= 1;
  us* xch  = (us*)ab((size_t)CH * Bn * XnP * 2);
  us* tmpb = (us*)ab((size_t)CH * Bn * Hn * 2);

  hipMemsetAsync(d_out, 0, 3 * sizeof(float), stream);
  hipMemsetAsync(fh_a, 0, 2 * (size_t)Bn * Hn * 2, stream);        // fh_a + h_a
  hipMemsetAsync(ghpre, 0, (size_t)Bn * 1536 * 4, stream);          // gh(h0=0) = 0

  const dim3 blk(256);
  auto CVT = [&](const float* s, us* d, size_t n) {
    cvt<<<dim3((unsigned)((n + 255) / 256)), blk, 0, stream>>>(s, d, (int)n);
  };

  {
    const size_t n = (size_t)512 * XnP;
    cvt_pad<<<dim3((unsigned)((n + 255) / 256)), blk, 0, stream>>>(pxW1, b_pxW1, Xn, XnP, (int)n);
  }
  CVT(pxW2, b_pxW2, (size_t)512 * 512);
  CVT(pzW, b_pzW, (size_t)512 * 64);
  CVT(pfW, b_pfW, (size_t)512 * 64);
  CVT(rWih, b_rWih, (size_t)1536 * 1536);
  CVT(rWhh, b_rWhh, (size_t)1536 * 512);
  CVT(zpW, b_zpW, (size_t)512 * 512);
  CVT(zpmW, b_zpmW, (size_t)64 * 512);
  CVT(zpsW, b_zpsW, (size_t)64 * 512);
  CVT(feWih, b_feWih, (size_t)1536 * 512);
  CVT(feWhh, b_feWhh, (size_t)1536 * 512);
  CVT(femW, b_femW, (size_t)64 * 512);
  CVT(fesW, b_fesW, (size_t)64 * 512);
  CVT(zeW1, b_zeW1, (size_t)512 * 1024);
  CVT(zeW2, b_zeW2, (size_t)512 * 512);
  CVT(zemW, b_zemW, (size_t)64 * 512);
  CVT(zesW, b_zesW, (size_t)64 * 512);
  CVT(dW1, b_dW1, (size_t)512 * 1536);
  CVT(dW2, b_dW2, (size_t)512 * 512);
  CVT(dmW, b_dmW, (size_t)Xn * 512);

  // ---- Phase A: phi_x ----
  for (int c = 0; c < Tn / CH; ++c) {
    const size_t nx = (size_t)CH * Bn * XnP;
    cvt_pad<<<dim3((unsigned)((nx + 255) / 256)), blk, 0, stream>>>(
        x + (size_t)c * CH * Bn * Xn, xch, Xn, XnP, (int)nx);
    const dim3 gA(8, CH * Bn / 64);
    k_gemmA<<<gA, blk, 0, stream>>>(xch, b_pxW1, XnP, XnP, pxb1, tmpb, Hn);
    k_gemmA<<<gA, blk, 0, stream>>>(tmpb, b_pxW2, Hn, Hn, pxb2,
                                    phi_x + (size_t)c * CH * Bn * Hn, Hn);
  }

  // ---- Phase B: f-encoder GRU ----
  us* fc = fh_a; us* fn2 = fh_b;
  for (int t = 0; t < Tn; ++t) {
    k_gruB<<<dim3(8, 8), blk, 0, stream>>>(
        phi_x + (size_t)t * Bn * Hn, b_feWih, fc, b_feWhh, febih, febhh, fn2);
    us* sw = fc; fc = fn2; fn2 = sw;
  }

  // ---- Phase C: f stats (final hidden is back in fh_a since Tn is even) ----
  k_statf<<<dim3(8), blk, 0, stream>>>(fh_a, b_femW, femb, b_fesW, fesb, eps_f, fbuf, out + 0);

  // ---- Prologue ----
  k_gemmA<<<dim3(8, 8), blk, 0, stream>>>(fbuf, b_pfW, Fn, Fn, pfb, phi_f, Hn);
  kP2<<<dim3(256), blk, 0, stream>>>(phi_f, b_rWih, b_dW1, db1, Cpre_gru, Cpre_dec);
  hipMemcpyAsync(dtmph, Cpre_dec, (size_t)Bn * 512 * 4, hipMemcpyDeviceToDevice, stream);
  kP3<<<dim3(128), blk, 0, stream>>>(h_a, b_zpW, zpb, zp, phi_x, b_zeW1, zeb1, zepre);
  kP4<<<dim3(72), blk, 0, stream>>>(zepre, b_zeW2, zeb2, ze,
                                    zp, b_zpmW, zpmb, b_zpsW, zpsb, zpm, zps);

  // ---- Phase D: 5 launches per timestep ----
  for (int t = 0; t < Tn; ++t) {
    const us* hcur = (t & 1) ? h_b : h_a;
    us* hnext      = (t & 1) ? h_a : h_b;
    const bool last = (t == Tn - 1);
    const us* px_t = phi_x + (size_t)t * Bn * Hn;

    kS1<<<dim3(200), blk, 0, stream>>>(
        ze, b_zemW, zemb, b_zesW, zesb, eps_z + (size_t)t * Bn * Zn, zpm, zps,
        zt, out + 1, px_t, b_rWih, Cpre_gru, gipre);

    kS2<<<dim3(64), blk, 0, stream>>>(zt, b_pzW, pzb, phiz);

    kS3<<<dim3(128), blk, 0, stream>>>(
        phiz, b_rWih, gipre, ghpre, hcur, rbih, rbhh, hnext,
        b_dW1, dtmph, dtmp);

    kS4<<<dim3(last ? 64 : 256), blk, 0, stream>>>(
        dtmp, b_dW2, db2, dec,
        hnext, b_zpW, zpb, zp,
        phi_x + (size_t)(t + 1) * Bn * Hn, b_zeW1, zeb1, zepre,
        b_dW1, Cpre_dec, dtmph);

    kS5<<<dim3(last ? 104 : 368), blk, 0, stream>>>(
        dec, b_dmW, dmb, x + (size_t)t * Bn * Xn, out + 2,
        zepre, b_zeW2, zeb2, ze,
        zp, b_zpmW, zpmb, b_zpsW, zpsb, zpm, zps,
        hnext, b_rWhh, ghpre);
  }
}